// Round 7
// baseline (3388.322 us; speedup 1.0000x reference)
//
#include <hip/hip_runtime.h>
#include <hip/hip_bf16.h>

// GatedMatchRNN: B=32, L1=128, L2=512, H=256
// Round 7: GRP=16 (512 blocks, 2 per CU) -> co-resident blocks of different
// batches overlap each other's barrier/L2 stalls; CU-paired blocks share the
// same weight slice (L1/L2 hot). RMW-arrive + load-poll barrier, bf16 weights,
// LDS-resident yp/y slices. Math identical to round 6.

#define B_ 32
#define L1_ 128
#define L2_ 512
#define H_ 256
#define GRP 16
#define TB 512
#define LOG2E_ 1.4426950408889634f

// ws layout (bytes)
#define YP_OFF   0u                        // bf16 [32][512][256] = 8 MB
#define XUP_OFF  (8u << 20)                // bf16 [32][128][256] = 2 MB
#define QP_OFF   (10u << 20)               // f32 [32][16][256] = 512 KB
#define CTP_OFF  (QP_OFF + (512u << 10))   // f32 [32][16][256] = 512 KB
#define ES_OFF   (CTP_OFF + (512u << 10))  // f32 [32][16] (padded 4 KB)
#define LI_OFF   (ES_OFF + (4u << 10))     // f32 [32][512] = 64 KB
#define HB_OFF   (LI_OFF + (64u << 10))    // f32 [32][256] = 32 KB
#define BAR_OFF  (HB_OFF + (32u << 10))    // uint counters [32][32] = 4 KB
#define WGB_OFF  (BAR_OFF + (4u << 10))    // bf16 Wg = 512 KB
#define WIHB_OFF (WGB_OFF + (512u << 10))  // bf16 Wih = 1 MB
#define WHHB_OFF (WIHB_OFF + (1024u << 10))// bf16 Whh = 512 KB
// end ~13.1 MB (ws >= 16 MB, proven round 2)

__device__ __forceinline__ float fexp2(float x) {
#if __has_builtin(__builtin_amdgcn_exp2f)
  return __builtin_amdgcn_exp2f(x);
#else
  return exp2f(x);
#endif
}
__device__ __forceinline__ float frcp(float x) {
#if __has_builtin(__builtin_amdgcn_rcpf)
  return __builtin_amdgcn_rcpf(x);
#else
  return 1.0f / x;
#endif
}
__device__ __forceinline__ float ftanh(float x) {
  return 1.0f - 2.0f * frcp(1.0f + fexp2(x * (2.0f * LOG2E_)));
}
__device__ __forceinline__ float fsig(float x) {
  return frcp(1.0f + fexp2(-x * LOG2E_));
}
__device__ __forceinline__ float dot4(float4 a, float4 b) {
  return a.x * b.x + a.y * b.y + a.z * b.z + a.w * b.w;
}
__device__ __forceinline__ float bfl(unsigned u) {
  return __uint_as_float(u << 16);
}
__device__ __forceinline__ float bfh(unsigned u) {
  return __uint_as_float(u & 0xffff0000u);
}
__device__ __forceinline__ unsigned short f2bf(float f) {
  __hip_bfloat16 b = __float2bfloat16(f);
  return *reinterpret_cast<unsigned short*>(&b);
}

// Per-access device-coherent load/store (sc0 sc1). No cache invalidates.
__device__ __forceinline__ float cload(const float* p) {
  return __hip_atomic_load(p, __ATOMIC_RELAXED, __HIP_MEMORY_SCOPE_AGENT);
}
__device__ __forceinline__ void cstore(float* p, float v) {
  __hip_atomic_store(p, v, __ATOMIC_RELAXED, __HIP_MEMORY_SCOPE_AGENT);
}

// Monotonic-counter barrier: all-wave vmcnt drain (data stores retired) ->
// RMW arrive (globally ordered at coherence point) -> relaxed load poll.
__device__ __forceinline__ void group_barrier(unsigned* cnt, unsigned target) {
  asm volatile("s_waitcnt vmcnt(0)" ::: "memory");
  __syncthreads();
  if (threadIdx.x == 0) {
    __hip_atomic_fetch_add(cnt, 1u, __ATOMIC_RELAXED,
                           __HIP_MEMORY_SCOPE_AGENT);
    while (__hip_atomic_load(cnt, __ATOMIC_RELAXED,
                             __HIP_MEMORY_SCOPE_AGENT) < GRP * target) {
      __builtin_amdgcn_s_sleep(1);
    }
  }
  __syncthreads();
  asm volatile("" ::: "memory");
}

// ---------------------------------------------------------------------------
// Projection: blocks 0..511 -> yp (bf16), 512..639 -> xup (bf16).
// ---------------------------------------------------------------------------
__global__ __launch_bounds__(256) void proj_kernel(
    const float* __restrict__ y, const float* __restrict__ Wq,
    const float* __restrict__ bq, const float* __restrict__ x,
    const float* __restrict__ Wup, const float* __restrict__ bup,
    __hip_bfloat16* __restrict__ yp, __hip_bfloat16* __restrict__ xup) {
  __shared__ float As[32 * 256];
  const int blk = blockIdx.x;
  const int tid = threadIdx.x;
  const float* src;
  const float* W;
  const float* bias;
  __hip_bfloat16* dst;
  int row0;
  if (blk < 512) {
    src = y; W = Wq; bias = bq; dst = yp; row0 = blk * 32;
  } else {
    src = x; W = Wup; bias = bup; dst = xup; row0 = (blk - 512) * 32;
  }
  const float4* s4 = (const float4*)(src + (size_t)row0 * H_);
  float4* A4 = (float4*)As;
#pragma unroll
  for (int i = 0; i < 8; ++i) A4[i * 256 + tid] = s4[i * 256 + tid];
  __syncthreads();

  const float4* w4 = (const float4*)(W + (size_t)tid * H_);
  float acc[32];
#pragma unroll
  for (int r = 0; r < 32; ++r) acc[r] = 0.0f;
  for (int kc = 0; kc < 64; ++kc) {
    float4 w = w4[kc];
#pragma unroll
    for (int r = 0; r < 32; ++r) acc[r] += dot4(A4[r * 64 + kc], w);
  }
  const float bb = bias[tid];
#pragma unroll 4
  for (int r = 0; r < 32; ++r)
    dst[(size_t)(row0 + r) * H_ + tid] = __float2bfloat16(acc[r] + bb);
}

// ---------------------------------------------------------------------------
// Weight conversion: Wg(512x512), Wih(1024x512), Whh(1024x256) -> bf16 in ws.
// ---------------------------------------------------------------------------
__global__ __launch_bounds__(256) void wconv_kernel(
    const float* __restrict__ Wg, const float* __restrict__ Wih,
    const float* __restrict__ Whh, unsigned short* __restrict__ wgb,
    unsigned short* __restrict__ wihb, unsigned short* __restrict__ whhb) {
  const int e = blockIdx.x * 256 + threadIdx.x;  // float4 index
  const float* src;
  unsigned short* dst;
  int off;
  if (e < 65536) {
    src = Wg; dst = wgb; off = e;
  } else if (e < 196608) {
    src = Wih; dst = wihb; off = e - 65536;
  } else {
    src = Whh; dst = whhb; off = e - 196608;
  }
  float4 v = ((const float4*)src)[off];
  ushort4 o;
  o.x = f2bf(v.x); o.y = f2bf(v.y); o.z = f2bf(v.z); o.w = f2bf(v.w);
  ((ushort4*)dst)[off] = o;
}

// ---------------------------------------------------------------------------
// Scan: block (b,g); b = blk>>4, g = blk&15. 512 threads, 2 blocks/CU.
// ---------------------------------------------------------------------------
__global__ __launch_bounds__(TB, 4) void scan_kernel(
    const float* __restrict__ x, const int* __restrict__ x_mask,
    const float* __restrict__ y, const int* __restrict__ y_mask,
    const float* __restrict__ h0, const float* __restrict__ c0,
    const float* __restrict__ Wvp, const float* __restrict__ bvp,
    const float* __restrict__ Vw, const float* __restrict__ Vb,
    const float* __restrict__ bg, const float* __restrict__ bih,
    const float* __restrict__ bhh, char* __restrict__ ws,
    float* __restrict__ out) {
  const int blk = blockIdx.x;
  const int b = blk >> 4;
  const int g = blk & 15;  // blk and blk+256 share g -> same weight slice/CU
  const int tid = threadIdx.x;

  const __hip_bfloat16* yp = (const __hip_bfloat16*)(ws + YP_OFF);
  const unsigned short* xupb = (const unsigned short*)(ws + XUP_OFF);
  float* qp = (float*)(ws + QP_OFF);
  float* ctp = (float*)(ws + CTP_OFF);
  float* esb = (float*)(ws + ES_OFF);
  float* lib = (float*)(ws + LI_OFF);
  float* hb = (float*)(ws + HB_OFF);
  unsigned* cnt = (unsigned*)(ws + BAR_OFF) + b * 32;  // 128B per batch
  const unsigned short* wgb = (const unsigned short*)(ws + WGB_OFF);
  const unsigned short* wihb = (const unsigned short*)(ws + WIHB_OFF);
  const unsigned short* whhb = (const unsigned short*)(ws + WHHB_OFF);

  __shared__ uint4 yp_lds[32 * 32];  // 16 KB, XOR-swizzled bf16 rows
  __shared__ float y_lds[32 * 256];  // 32 KB f32
  __shared__ __align__(16) float h_s[H_];
  __shared__ float q_s[H_];
  __shared__ float v_s[H_];
  __shared__ float bvp_s[H_];
  __shared__ float e_s[32];
  __shared__ __align__(16) float mg_s[2 * H_];
  __shared__ __align__(16) float li_s[2 * H_];
  __shared__ float gate_s[64];
  __shared__ float red_s[576];
  __shared__ float esum_s[16];
  __shared__ __align__(16) float c_s[16];
  __shared__ __align__(16) float hn_s[16];
  __shared__ float bg_s[32];
  __shared__ float bi_s[64];
  __shared__ int ym_s[32];
  __shared__ int xm_s[L1_];

  unsigned target = 0;

  // ---- stage t-invariant data (rows [g*32, g*32+32) of yp/y) ----
  {
    const uint4* src = (const uint4*)(yp + (size_t)(b * L2_ + g * 32) * H_);
    for (int k = tid; k < 32 * 32; k += TB) {
      int r = k >> 5, c = k & 31;
      yp_lds[r * 32 + (c ^ r)] = src[k];  // XOR swizzle: no bank conflicts
    }
    const float4* ys = (const float4*)(y + (size_t)(b * L2_ + g * 32) * H_);
    float4* yd = (float4*)y_lds;
    for (int k = tid; k < 32 * 64; k += TB) yd[k] = ys[k];
  }
  if (tid < H_) {
    v_s[tid] = Vw[tid];
    bvp_s[tid] = bvp[tid];
  }
  if (tid < 32) {
    ym_s[tid] = y_mask[b * L2_ + g * 32 + tid];
    bg_s[tid] = bg[g * 32 + tid];
  }
  if (tid < 64) {
    const int grow = (tid >> 4) * H_ + g * 16 + (tid & 15);
    bi_s[tid] = bih[grow] + bhh[grow];
  }
  if (tid < 128) xm_s[tid] = x_mask[b * L1_ + tid];
  if (tid < 16) {
    float hv = h0[b * H_ + g * 16 + tid];
    c_s[tid] = c0[b * H_ + g * 16 + tid];
    hn_s[tid] = hv;
    cstore(&hb[b * H_ + g * 16 + tid], hv);
  }
  const float vb = Vb[0];
  __syncthreads();
  {  // initial qpart from h0 slice (16 cols of Wvp)
    const int j = tid >> 1, sub = tid & 1;
    const float4* w4 = (const float4*)(Wvp + (size_t)j * H_ + g * 16 + sub * 8);
    const float4* hv4 = (const float4*)(hn_s + sub * 8);
    float acc = dot4(w4[0], hv4[0]) + dot4(w4[1], hv4[1]);
    acc += __shfl_xor(acc, 1);
    if (sub == 0) cstore(&qp[(b * GRP + g) * H_ + j], acc);
  }
  group_barrier(cnt, ++target);

  for (int t = 0; t < L1_; ++t) {
    const int xm = xm_s[t];

    // ---- q finalize + load prev h (coherent reads) ------------------------
    if (tid < H_) {
      h_s[tid] = cload(&hb[b * H_ + tid]);
      float acc = bvp_s[tid] + bfl(xupb[(size_t)(b * L1_ + t) * H_ + tid]);
#pragma unroll
      for (int g2 = 0; g2 < GRP; ++g2)
        acc += cload(&qp[(b * GRP + g2) * H_ + tid]);
      q_s[tid] = acc;
    }
    __syncthreads();

    // ---- B: scores for l-slice [g*32, g*32+32) ----------------------------
    {
      const int l = tid & 31, sub = tid >> 5;  // sub: 16 chunks of 16 h
      float acc = 0.f;
#pragma unroll
      for (int i = 0; i < 2; ++i) {
        uint4 u = yp_lds[l * 32 + ((sub * 2 + i) ^ l)];
        const int h = sub * 16 + i * 8;
        acc += v_s[h + 0] * ftanh(q_s[h + 0] + bfl(u.x));
        acc += v_s[h + 1] * ftanh(q_s[h + 1] + bfh(u.x));
        acc += v_s[h + 2] * ftanh(q_s[h + 2] + bfl(u.y));
        acc += v_s[h + 3] * ftanh(q_s[h + 3] + bfh(u.y));
        acc += v_s[h + 4] * ftanh(q_s[h + 4] + bfl(u.z));
        acc += v_s[h + 5] * ftanh(q_s[h + 5] + bfh(u.z));
        acc += v_s[h + 6] * ftanh(q_s[h + 6] + bfl(u.w));
        acc += v_s[h + 7] * ftanh(q_s[h + 7] + bfh(u.w));
      }
      red_s[l * 17 + sub] = acc;  // stride 17: conflict-light
    }
    __syncthreads();
    if (tid < 32) {
      float s = vb;
#pragma unroll
      for (int k = 0; k < 16; ++k) s += red_s[tid * 17 + k];
      // |s| <= |Vb| + sum|v| ~ 13 -> exp never overflows; no global max
      float e = ym_s[tid] ? 0.f : fexp2(s * LOG2E_);
      e_s[tid] = e;
      float ss = e;
#pragma unroll
      for (int off = 16; off >= 1; off >>= 1) ss += __shfl_xor(ss, off);
      if (tid == 0) cstore(&esb[b * GRP + g], ss);
    }
    __syncthreads();

    // ---- ct partial over the l-slice (y from LDS) -------------------------
    {
      const int d = tid & 255, part = tid >> 8;
      float acc = 0.f;
#pragma unroll 8
      for (int i = 0; i < 16; ++i)
        acc += e_s[part * 16 + i] * y_lds[(part * 16 + i) * 256 + d];
      red_s[tid] = acc;
    }
    __syncthreads();
    if (tid < H_)
      cstore(&ctp[(b * GRP + g) * H_ + tid], red_s[tid] + red_s[tid + 256]);
    group_barrier(cnt, ++target);

    // ---- ct finalize + merge ---------------------------------------------
    if (tid < GRP) esum_s[tid] = cload(&esb[b * GRP + tid]);
    if (tid < H_) mg_s[tid] = x[(size_t)(b * L1_ + t) * H_ + tid];
    __syncthreads();
    if (tid < H_) {
      float tot = 0.f;
#pragma unroll
      for (int k = 0; k < GRP; ++k) tot += esum_s[k];
      float ctv = 0.f;
#pragma unroll
      for (int g2 = 0; g2 < GRP; ++g2)
        ctv += cload(&ctp[(b * GRP + g2) * H_ + tid]);
      mg_s[H_ + tid] = ctv * frcp(tot);
    }
    __syncthreads();

    // ---- E: li-slice [g*32, g*32+32), Wg bf16 -----------------------------
    {
      const int o = tid >> 4, sub = tid & 15;
      const uint4* wrow = (const uint4*)(wgb + (size_t)(g * 32 + o) * 512);
      const float4* m4 = (const float4*)mg_s;
      float acc = 0.f;
#pragma unroll
      for (int jj = 0; jj < 4; ++jj) {
        const int c = sub + 16 * jj;
        uint4 u = wrow[c];
        float4 ma = m4[c * 2], mb = m4[c * 2 + 1];
        acc += bfl(u.x) * ma.x + bfh(u.x) * ma.y + bfl(u.y) * ma.z +
               bfh(u.y) * ma.w + bfl(u.z) * mb.x + bfh(u.z) * mb.y +
               bfl(u.w) * mb.z + bfh(u.w) * mb.w;
      }
      acc += __shfl_xor(acc, 1);
      acc += __shfl_xor(acc, 2);
      acc += __shfl_xor(acc, 4);
      acc += __shfl_xor(acc, 8);
      if (sub == 0) {
        float gt = fsig(acc + bg_s[o]);
        cstore(&lib[b * 512 + g * 32 + o], xm ? 0.f : gt * mg_s[g * 32 + o]);
      }
    }
    group_barrier(cnt, ++target);

    // ---- F: gates for h-dims [g*16, g*16+16), Wih/Whh bf16 ----------------
    li_s[tid] = cload(&lib[b * 512 + tid]);
    __syncthreads();
    {
      const int r = tid >> 3, sub = tid & 7;  // 64 gate rows, 8-way K split
      const int grow = (r >> 4) * H_ + g * 16 + (r & 15);
      const uint4* wi = (const uint4*)(wihb + (size_t)grow * 512);
      const uint4* wh = (const uint4*)(whhb + (size_t)grow * 256);
      const float4* l4 = (const float4*)li_s;
      const float4* h4 = (const float4*)h_s;
      float acc = 0.f;
#pragma unroll
      for (int jj = 0; jj < 8; ++jj) {
        const int c = sub + 8 * jj;
        uint4 u = wi[c];
        float4 a = l4[c * 2], c2 = l4[c * 2 + 1];
        acc += bfl(u.x) * a.x + bfh(u.x) * a.y + bfl(u.y) * a.z +
               bfh(u.y) * a.w + bfl(u.z) * c2.x + bfh(u.z) * c2.y +
               bfl(u.w) * c2.z + bfh(u.w) * c2.w;
      }
#pragma unroll
      for (int jj = 0; jj < 4; ++jj) {
        const int c = sub + 8 * jj;
        uint4 u = wh[c];
        float4 a = h4[c * 2], c2 = h4[c * 2 + 1];
        acc += bfl(u.x) * a.x + bfh(u.x) * a.y + bfl(u.y) * a.z +
               bfh(u.y) * a.w + bfl(u.z) * c2.x + bfh(u.z) * c2.y +
               bfl(u.w) * c2.z + bfh(u.w) * c2.w;
      }
      acc += __shfl_xor(acc, 1);
      acc += __shfl_xor(acc, 2);
      acc += __shfl_xor(acc, 4);
      if (sub == 0) gate_s[r] = acc + bi_s[r];
    }
    __syncthreads();
    if (tid < 16) {
      float ii = gate_s[tid], ff = gate_s[16 + tid];
      float gg = gate_s[32 + tid], oo = gate_s[48 + tid];
      float cn = fsig(ff) * c_s[tid] + fsig(ii) * ftanh(gg);
      float hn = xm ? 0.f : fsig(oo) * ftanh(cn);
      c_s[tid] = cn;
      hn_s[tid] = hn;
      cstore(&hb[b * H_ + g * 16 + tid], hn);
      out[(size_t)(b * L1_ + t) * H_ + g * 16 + tid] = hn;
    }
    __syncthreads();

    // ---- A': qpart for next step from new h slice (Wvp f32) ---------------
    {
      const int j = tid >> 1, sub = tid & 1;
      const float4* w4 =
          (const float4*)(Wvp + (size_t)j * H_ + g * 16 + sub * 8);
      const float4* hv4 = (const float4*)(hn_s + sub * 8);
      float acc = dot4(w4[0], hv4[0]) + dot4(w4[1], hv4[1]);
      acc += __shfl_xor(acc, 1);
      if (sub == 0) cstore(&qp[(b * GRP + g) * H_ + j], acc);
    }
    group_barrier(cnt, ++target);
  }
}

extern "C" void kernel_launch(void* const* d_in, const int* in_sizes, int n_in,
                              void* d_out, int out_size, void* d_ws,
                              size_t ws_size, hipStream_t stream) {
  const float* x = (const float*)d_in[0];
  const int* x_mask = (const int*)d_in[1];
  const float* y = (const float*)d_in[2];
  const int* y_mask = (const int*)d_in[3];
  const float* h0 = (const float*)d_in[4];
  const float* c0 = (const float*)d_in[5];
  const float* Wq = (const float*)d_in[6];
  const float* bq = (const float*)d_in[7];
  const float* Wup = (const float*)d_in[8];
  const float* bup = (const float*)d_in[9];
  const float* Wvp = (const float*)d_in[10];
  const float* bvp = (const float*)d_in[11];
  const float* Vw = (const float*)d_in[12];
  const float* Vb = (const float*)d_in[13];
  const float* Wg = (const float*)d_in[14];
  const float* bg = (const float*)d_in[15];
  const float* Wih = (const float*)d_in[16];
  const float* Whh = (const float*)d_in[17];
  const float* bih = (const float*)d_in[18];
  const float* bhh = (const float*)d_in[19];

  float* out = (float*)d_out;
  char* ws = (char*)d_ws;

  hipMemsetAsync(ws + BAR_OFF, 0, 4096, stream);  // barrier counters -> 0
  proj_kernel<<<dim3(640), dim3(256), 0, stream>>>(
      y, Wq, bq, x, Wup, bup, (__hip_bfloat16*)(ws + YP_OFF),
      (__hip_bfloat16*)(ws + XUP_OFF));
  wconv_kernel<<<dim3(1024), dim3(256), 0, stream>>>(
      Wg, Wih, Whh, (unsigned short*)(ws + WGB_OFF),
      (unsigned short*)(ws + WIHB_OFF), (unsigned short*)(ws + WHHB_OFF));
  scan_kernel<<<dim3(B_ * GRP), dim3(TB), 0, stream>>>(
      x, x_mask, y, y_mask, h0, c0, Wvp, bvp, Vw, Vb, bg, bih, bhh, ws, out);
}

// Round 8
// 1539.323 us; speedup vs baseline: 2.2012x; 2.2012x over previous
//
#include <hip/hip_runtime.h>
#include <hip/hip_bf16.h>

// GatedMatchRNN: B=32, L1=128, L2=512, H=256
// Round 8: r6 base (GRP=8, proven 1656us) + (1) XCD-local group mapping
// (b=blk&31: a batch's 8 blocks share one XCD -> intra-XCD barriers/comm),
// (2) RMW-arrive + load-poll barrier, (3) finalize loads spread over all
// 512 threads. Math identical to r6.

#define B_ 32
#define L1_ 128
#define L2_ 512
#define H_ 256
#define GRP 8
#define TB 512
#define LOG2E_ 1.4426950408889634f

// ws layout (bytes)
#define YP_OFF   0u                        // bf16 [32][512][256] = 8 MB
#define XUP_OFF  (8u << 20)                // bf16 [32][128][256] = 2 MB
#define QP_OFF   (10u << 20)               // f32 [32][8][256] = 256 KB
#define CTP_OFF  (QP_OFF + (256u << 10))   // f32 [32][8][256] = 256 KB
#define ES_OFF   (CTP_OFF + (256u << 10))  // f32 [32][8] (padded 4 KB)
#define LI_OFF   (ES_OFF + (4u << 10))     // f32 [32][512] = 64 KB
#define HB_OFF   (LI_OFF + (64u << 10))    // f32 [32][256] = 32 KB
#define BAR_OFF  (HB_OFF + (32u << 10))    // uint counters [32][32] = 4 KB
#define WGB_OFF  (BAR_OFF + (4u << 10))    // bf16 Wg = 512 KB
#define WIHB_OFF (WGB_OFF + (512u << 10))  // bf16 Wih = 1 MB
#define WHHB_OFF (WIHB_OFF + (1024u << 10))// bf16 Whh = 512 KB
// end ~12.6 MB (ws >= 16 MB, proven round 2)

__device__ __forceinline__ float fexp2(float x) {
#if __has_builtin(__builtin_amdgcn_exp2f)
  return __builtin_amdgcn_exp2f(x);
#else
  return exp2f(x);
#endif
}
__device__ __forceinline__ float frcp(float x) {
#if __has_builtin(__builtin_amdgcn_rcpf)
  return __builtin_amdgcn_rcpf(x);
#else
  return 1.0f / x;
#endif
}
__device__ __forceinline__ float ftanh(float x) {
  return 1.0f - 2.0f * frcp(1.0f + fexp2(x * (2.0f * LOG2E_)));
}
__device__ __forceinline__ float fsig(float x) {
  return frcp(1.0f + fexp2(-x * LOG2E_));
}
__device__ __forceinline__ float dot4(float4 a, float4 b) {
  return a.x * b.x + a.y * b.y + a.z * b.z + a.w * b.w;
}
__device__ __forceinline__ float bfl(unsigned u) {
  return __uint_as_float(u << 16);
}
__device__ __forceinline__ float bfh(unsigned u) {
  return __uint_as_float(u & 0xffff0000u);
}
__device__ __forceinline__ unsigned short f2bf(float f) {
  __hip_bfloat16 b = __float2bfloat16(f);
  return *reinterpret_cast<unsigned short*>(&b);
}

// Per-access device-coherent load/store (sc0 sc1). No cache invalidates.
__device__ __forceinline__ float cload(const float* p) {
  return __hip_atomic_load(p, __ATOMIC_RELAXED, __HIP_MEMORY_SCOPE_AGENT);
}
__device__ __forceinline__ void cstore(float* p, float v) {
  __hip_atomic_store(p, v, __ATOMIC_RELAXED, __HIP_MEMORY_SCOPE_AGENT);
}

// Monotonic-counter barrier: all-wave vmcnt drain (data stores retired) ->
// RMW arrive (globally ordered, r6-proven) -> relaxed LOAD poll (r7-proven;
// avoids poll-RMWs serializing against arrivals on the counter line).
__device__ __forceinline__ void group_barrier(unsigned* cnt, unsigned target) {
  asm volatile("s_waitcnt vmcnt(0)" ::: "memory");
  __syncthreads();
  if (threadIdx.x == 0) {
    __hip_atomic_fetch_add(cnt, 1u, __ATOMIC_RELAXED,
                           __HIP_MEMORY_SCOPE_AGENT);
    while (__hip_atomic_load(cnt, __ATOMIC_RELAXED,
                             __HIP_MEMORY_SCOPE_AGENT) < GRP * target) {
      __builtin_amdgcn_s_sleep(1);
    }
  }
  __syncthreads();
  asm volatile("" ::: "memory");
}

// ---------------------------------------------------------------------------
// Projection: blocks 0..511 -> yp (bf16), 512..639 -> xup (bf16).
// ---------------------------------------------------------------------------
__global__ __launch_bounds__(256) void proj_kernel(
    const float* __restrict__ y, const float* __restrict__ Wq,
    const float* __restrict__ bq, const float* __restrict__ x,
    const float* __restrict__ Wup, const float* __restrict__ bup,
    __hip_bfloat16* __restrict__ yp, __hip_bfloat16* __restrict__ xup) {
  __shared__ float As[32 * 256];
  const int blk = blockIdx.x;
  const int tid = threadIdx.x;
  const float* src;
  const float* W;
  const float* bias;
  __hip_bfloat16* dst;
  int row0;
  if (blk < 512) {
    src = y; W = Wq; bias = bq; dst = yp; row0 = blk * 32;
  } else {
    src = x; W = Wup; bias = bup; dst = xup; row0 = (blk - 512) * 32;
  }
  const float4* s4 = (const float4*)(src + (size_t)row0 * H_);
  float4* A4 = (float4*)As;
#pragma unroll
  for (int i = 0; i < 8; ++i) A4[i * 256 + tid] = s4[i * 256 + tid];
  __syncthreads();

  const float4* w4 = (const float4*)(W + (size_t)tid * H_);
  float acc[32];
#pragma unroll
  for (int r = 0; r < 32; ++r) acc[r] = 0.0f;
  for (int kc = 0; kc < 64; ++kc) {
    float4 w = w4[kc];
#pragma unroll
    for (int r = 0; r < 32; ++r) acc[r] += dot4(A4[r * 64 + kc], w);
  }
  const float bb = bias[tid];
#pragma unroll 4
  for (int r = 0; r < 32; ++r)
    dst[(size_t)(row0 + r) * H_ + tid] = __float2bfloat16(acc[r] + bb);
}

// ---------------------------------------------------------------------------
// Weight conversion: Wg(512x512), Wih(1024x512), Whh(1024x256) -> bf16 in ws.
// ---------------------------------------------------------------------------
__global__ __launch_bounds__(256) void wconv_kernel(
    const float* __restrict__ Wg, const float* __restrict__ Wih,
    const float* __restrict__ Whh, unsigned short* __restrict__ wgb,
    unsigned short* __restrict__ wihb, unsigned short* __restrict__ whhb) {
  const int e = blockIdx.x * 256 + threadIdx.x;  // float4 index
  const float* src;
  unsigned short* dst;
  int off;
  if (e < 65536) {
    src = Wg; dst = wgb; off = e;
  } else if (e < 196608) {
    src = Wih; dst = wihb; off = e - 65536;
  } else {
    src = Whh; dst = whhb; off = e - 196608;
  }
  float4 v = ((const float4*)src)[off];
  ushort4 o;
  o.x = f2bf(v.x); o.y = f2bf(v.y); o.z = f2bf(v.z); o.w = f2bf(v.w);
  ((ushort4*)dst)[off] = o;
}

// ---------------------------------------------------------------------------
// Scan: block (b,g); b = blk&31, g = blk>>5. 512 threads, 1 block/CU.
// XCD-local mapping: blocks {g*32+b, g=0..7} all have blk%8 == b%8 -> one XCD.
// ---------------------------------------------------------------------------
__global__ __launch_bounds__(TB) void scan_kernel(
    const float* __restrict__ x, const int* __restrict__ x_mask,
    const float* __restrict__ y, const int* __restrict__ y_mask,
    const float* __restrict__ h0, const float* __restrict__ c0,
    const float* __restrict__ Wvp, const float* __restrict__ bvp,
    const float* __restrict__ Vw, const float* __restrict__ Vb,
    const float* __restrict__ bg, const float* __restrict__ bih,
    const float* __restrict__ bhh, char* __restrict__ ws,
    float* __restrict__ out) {
  const int blk = blockIdx.x;
  const int b = blk & 31;   // batch; all 8 g-blocks of b share one XCD
  const int g = blk >> 5;   // slice
  const int tid = threadIdx.x;

  const __hip_bfloat16* yp = (const __hip_bfloat16*)(ws + YP_OFF);
  const unsigned short* xupb = (const unsigned short*)(ws + XUP_OFF);
  float* qp = (float*)(ws + QP_OFF);
  float* ctp = (float*)(ws + CTP_OFF);
  float* esb = (float*)(ws + ES_OFF);
  float* lib = (float*)(ws + LI_OFF);
  float* hb = (float*)(ws + HB_OFF);
  unsigned* cnt = (unsigned*)(ws + BAR_OFF) + b * 32;  // 128B per batch
  const unsigned short* wgb = (const unsigned short*)(ws + WGB_OFF);
  const unsigned short* wihb = (const unsigned short*)(ws + WIHB_OFF);
  const unsigned short* whhb = (const unsigned short*)(ws + WHHB_OFF);

  __shared__ uint4 yp_lds[64 * 32];  // 32 KB, XOR-swizzled bf16 rows
  __shared__ float y_lds[64 * 256];  // 64 KB
  __shared__ __align__(16) float h_s[H_];
  __shared__ float q_s[H_];
  __shared__ float v_s[H_];
  __shared__ float bvp_s[H_];
  __shared__ float e_s[64];
  __shared__ __align__(16) float mg_s[2 * H_];
  __shared__ __align__(16) float li_s[2 * H_];
  __shared__ float gate_s[128];
  __shared__ float red_s[64 * 9];
  __shared__ float esum_s[8];
  __shared__ __align__(16) float c_s[32];
  __shared__ __align__(16) float hn_s[32];
  __shared__ float bg_s[64];
  __shared__ float bi_s[128];
  __shared__ int ym_s[64];
  __shared__ int xm_s[L1_];

  unsigned target = 0;

  // ---- stage t-invariant data ----
  {
    const uint4* src = (const uint4*)(yp + (size_t)(b * L2_ + g * 64) * H_);
    for (int k = tid; k < 64 * 32; k += TB) {
      int r = k >> 5, c = k & 31;
      yp_lds[r * 32 + (c ^ (r & 31))] = src[k];  // swizzle kills bank conflicts
    }
    const float4* ys = (const float4*)(y + (size_t)(b * L2_ + g * 64) * H_);
    float4* yd = (float4*)y_lds;
    for (int k = tid; k < 64 * 64; k += TB) yd[k] = ys[k];
  }
  if (tid < H_) {
    v_s[tid] = Vw[tid];
    bvp_s[tid] = bvp[tid];
  }
  if (tid < 64) {
    ym_s[tid] = y_mask[b * L2_ + g * 64 + tid];
    bg_s[tid] = bg[g * 64 + tid];
  }
  if (tid < 128) {
    xm_s[tid] = x_mask[b * L1_ + tid];
    const int grow = (tid >> 5) * H_ + g * 32 + (tid & 31);
    bi_s[tid] = bih[grow] + bhh[grow];
  }
  if (tid < 32) {
    float hv = h0[b * H_ + g * 32 + tid];
    c_s[tid] = c0[b * H_ + g * 32 + tid];
    hn_s[tid] = hv;
    cstore(&hb[b * H_ + g * 32 + tid], hv);
  }
  const float vb = Vb[0];
  __syncthreads();
  {  // initial qpart from h0 slice (column-split of Wvp, f32)
    const int j = tid >> 1, sub = tid & 1;
    const float4* w4 =
        (const float4*)(Wvp + (size_t)j * H_ + g * 32 + sub * 16);
    const float4* hv4 = (const float4*)(hn_s + sub * 16);
    float acc = 0.f;
#pragma unroll
    for (int i = 0; i < 4; ++i) acc += dot4(w4[i], hv4[i]);
    acc += __shfl_xor(acc, 1);
    if (sub == 0) cstore(&qp[(b * 8 + g) * H_ + j], acc);
  }
  group_barrier(cnt, ++target);

  for (int t = 0; t < L1_; ++t) {
    const int xm = xm_s[t];

    // ---- q finalize (spread over 512 threads) + load prev h ---------------
    {
      const int j = tid & 255, half = tid >> 8;
      float acc = 0.f;
#pragma unroll
      for (int k = 0; k < 4; ++k)
        acc += cload(&qp[(b * 8 + half * 4 + k) * H_ + j]);
      red_s[half * 256 + j] = acc;
      if (tid < H_) h_s[tid] = cload(&hb[b * H_ + tid]);
    }
    __syncthreads();
    if (tid < H_) {
      q_s[tid] = red_s[tid] + red_s[256 + tid] + bvp_s[tid] +
                 bfl(xupb[(size_t)(b * L1_ + t) * H_ + tid]);
    }
    __syncthreads();

    // ---- B: scores for l-slice [g*64, g*64+64), yp from swizzled LDS ------
    {
      const int l = tid & 63, sub = tid >> 6;
      float acc = 0.f;
#pragma unroll
      for (int i = 0; i < 4; ++i) {
        uint4 u = yp_lds[l * 32 + ((sub * 4 + i) ^ (l & 31))];
        const int h = sub * 32 + i * 8;
        acc += v_s[h + 0] * ftanh(q_s[h + 0] + bfl(u.x));
        acc += v_s[h + 1] * ftanh(q_s[h + 1] + bfh(u.x));
        acc += v_s[h + 2] * ftanh(q_s[h + 2] + bfl(u.y));
        acc += v_s[h + 3] * ftanh(q_s[h + 3] + bfh(u.y));
        acc += v_s[h + 4] * ftanh(q_s[h + 4] + bfl(u.z));
        acc += v_s[h + 5] * ftanh(q_s[h + 5] + bfh(u.z));
        acc += v_s[h + 6] * ftanh(q_s[h + 6] + bfl(u.w));
        acc += v_s[h + 7] * ftanh(q_s[h + 7] + bfh(u.w));
      }
      red_s[l * 9 + sub] = acc;  // stride 9 (2-way max, free)
    }
    __syncthreads();
    if (tid < 64) {
      float s = vb;
#pragma unroll
      for (int k = 0; k < 8; ++k) s += red_s[tid * 9 + k];
      // |s| <= |Vb| + sum|v| ~ 13 -> exp never overflows; no global max
      float e = ym_s[tid] ? 0.f : fexp2(s * LOG2E_);
      e_s[tid] = e;
      float ss = e;
#pragma unroll
      for (int off = 32; off >= 1; off >>= 1) ss += __shfl_xor(ss, off);
      if (tid == 0) cstore(&esb[b * 8 + g], ss);
    }
    __syncthreads();

    // ---- ct partial over the l-slice (y from LDS) -------------------------
    {
      const int d = tid & 255, part = tid >> 8;
      float acc = 0.f;
#pragma unroll 8
      for (int i = 0; i < 32; ++i)
        acc += e_s[part * 32 + i] * y_lds[(part * 32 + i) * 256 + d];
      __syncthreads();
      red_s[tid] = acc;
    }
    __syncthreads();
    if (tid < H_)
      cstore(&ctp[(b * 8 + g) * H_ + tid], red_s[tid] + red_s[tid + 256]);
    group_barrier(cnt, ++target);

    // ---- ct finalize (spread over 512 threads) + merge --------------------
    if (tid < 8) esum_s[tid] = cload(&esb[b * 8 + tid]);
    {
      const int j = tid & 255, half = tid >> 8;
      float acc = 0.f;
#pragma unroll
      for (int k = 0; k < 4; ++k)
        acc += cload(&ctp[(b * 8 + half * 4 + k) * H_ + j]);
      red_s[half * 256 + j] = acc;
      if (tid < H_) mg_s[tid] = x[(size_t)(b * L1_ + t) * H_ + tid];
    }
    __syncthreads();
    if (tid < H_) {
      float tot = esum_s[0] + esum_s[1] + esum_s[2] + esum_s[3] + esum_s[4] +
                  esum_s[5] + esum_s[6] + esum_s[7];
      mg_s[H_ + tid] = (red_s[tid] + red_s[256 + tid]) * frcp(tot);
    }
    __syncthreads();

    // ---- E: li-slice [g*64, g*64+64), Wg bf16 -----------------------------
    {
      const int o = tid >> 3, sub = tid & 7;
      const uint4* wrow = (const uint4*)(wgb + (size_t)(g * 64 + o) * 512);
      const float4* m4 = (const float4*)mg_s;
      float acc = 0.f;
#pragma unroll
      for (int j = 0; j < 8; ++j) {
        uint4 u = wrow[sub + 8 * j];
        float4 ma = m4[(sub + 8 * j) * 2], mb = m4[(sub + 8 * j) * 2 + 1];
        acc += bfl(u.x) * ma.x + bfh(u.x) * ma.y + bfl(u.y) * ma.z +
               bfh(u.y) * ma.w + bfl(u.z) * mb.x + bfh(u.z) * mb.y +
               bfl(u.w) * mb.z + bfh(u.w) * mb.w;
      }
      acc += __shfl_xor(acc, 1);
      acc += __shfl_xor(acc, 2);
      acc += __shfl_xor(acc, 4);
      if (sub == 0) {
        float gt = fsig(acc + bg_s[o]);
        cstore(&lib[b * 512 + g * 64 + o], xm ? 0.f : gt * mg_s[g * 64 + o]);
      }
    }
    group_barrier(cnt, ++target);

    // ---- F: gates for h-dims [g*32, g*32+32), Wih/Whh bf16 ----------------
    li_s[tid] = cload(&lib[b * 512 + tid]);
    __syncthreads();
    {
      const int r = tid >> 2, sub = tid & 3;
      const int grow = (r >> 5) * H_ + g * 32 + (r & 31);
      const uint4* wi = (const uint4*)(wihb + (size_t)grow * 512);
      const uint4* wh = (const uint4*)(whhb + (size_t)grow * 256);
      const float4* l4 = (const float4*)li_s;
      const float4* h4 = (const float4*)h_s;
      float acc = 0.f;
#pragma unroll
      for (int j = 0; j < 16; ++j) {
        uint4 u = wi[sub + 4 * j];
        float4 a = l4[(sub + 4 * j) * 2], c2 = l4[(sub + 4 * j) * 2 + 1];
        acc += bfl(u.x) * a.x + bfh(u.x) * a.y + bfl(u.y) * a.z +
               bfh(u.y) * a.w + bfl(u.z) * c2.x + bfh(u.z) * c2.y +
               bfl(u.w) * c2.z + bfh(u.w) * c2.w;
      }
#pragma unroll
      for (int j = 0; j < 8; ++j) {
        uint4 u = wh[sub + 4 * j];
        float4 a = h4[(sub + 4 * j) * 2], c2 = h4[(sub + 4 * j) * 2 + 1];
        acc += bfl(u.x) * a.x + bfh(u.x) * a.y + bfl(u.y) * a.z +
               bfh(u.y) * a.w + bfl(u.z) * c2.x + bfh(u.z) * c2.y +
               bfl(u.w) * c2.z + bfh(u.w) * c2.w;
      }
      acc += __shfl_xor(acc, 1);
      acc += __shfl_xor(acc, 2);
      if (sub == 0) gate_s[r] = acc + bi_s[r];
    }
    __syncthreads();
    if (tid < 32) {
      float ii = gate_s[tid], ff = gate_s[32 + tid];
      float gg = gate_s[64 + tid], oo = gate_s[96 + tid];
      float cn = fsig(ff) * c_s[tid] + fsig(ii) * ftanh(gg);
      float hn = xm ? 0.f : fsig(oo) * ftanh(cn);
      c_s[tid] = cn;
      hn_s[tid] = hn;
      cstore(&hb[b * H_ + g * 32 + tid], hn);
      out[(size_t)(b * L1_ + t) * H_ + g * 32 + tid] = hn;
    }
    __syncthreads();

    // ---- A': qpart for next step from new h slice (Wvp f32) ---------------
    {
      const int j = tid >> 1, sub = tid & 1;
      const float4* w4 =
          (const float4*)(Wvp + (size_t)j * H_ + g * 32 + sub * 16);
      const float4* hv4 = (const float4*)(hn_s + sub * 16);
      float acc = 0.f;
#pragma unroll
      for (int i = 0; i < 4; ++i) acc += dot4(w4[i], hv4[i]);
      acc += __shfl_xor(acc, 1);
      if (sub == 0) cstore(&qp[(b * 8 + g) * H_ + j], acc);
    }
    group_barrier(cnt, ++target);
  }
}

extern "C" void kernel_launch(void* const* d_in, const int* in_sizes, int n_in,
                              void* d_out, int out_size, void* d_ws,
                              size_t ws_size, hipStream_t stream) {
  const float* x = (const float*)d_in[0];
  const int* x_mask = (const int*)d_in[1];
  const float* y = (const float*)d_in[2];
  const int* y_mask = (const int*)d_in[3];
  const float* h0 = (const float*)d_in[4];
  const float* c0 = (const float*)d_in[5];
  const float* Wq = (const float*)d_in[6];
  const float* bq = (const float*)d_in[7];
  const float* Wup = (const float*)d_in[8];
  const float* bup = (const float*)d_in[9];
  const float* Wvp = (const float*)d_in[10];
  const float* bvp = (const float*)d_in[11];
  const float* Vw = (const float*)d_in[12];
  const float* Vb = (const float*)d_in[13];
  const float* Wg = (const float*)d_in[14];
  const float* bg = (const float*)d_in[15];
  const float* Wih = (const float*)d_in[16];
  const float* Whh = (const float*)d_in[17];
  const float* bih = (const float*)d_in[18];
  const float* bhh = (const float*)d_in[19];

  float* out = (float*)d_out;
  char* ws = (char*)d_ws;

  hipMemsetAsync(ws + BAR_OFF, 0, 4096, stream);  // barrier counters -> 0
  proj_kernel<<<dim3(640), dim3(256), 0, stream>>>(
      y, Wq, bq, x, Wup, bup, (__hip_bfloat16*)(ws + YP_OFF),
      (__hip_bfloat16*)(ws + XUP_OFF));
  wconv_kernel<<<dim3(1024), dim3(256), 0, stream>>>(
      Wg, Wih, Whh, (unsigned short*)(ws + WGB_OFF),
      (unsigned short*)(ws + WIHB_OFF), (unsigned short*)(ws + WHHB_OFF));
  scan_kernel<<<dim3(B_ * GRP), dim3(TB), 0, stream>>>(
      x, x_mask, y, y_mask, h0, c0, Wvp, bvp, Vw, Vb, bg, bih, bhh, ws, out);
}